// Round 5
// baseline (446.013 us; speedup 1.0000x reference)
//
#include <hip/hip_runtime.h>
#include <math.h>

#define BATCH 32
#define CI 8
#define CO 8
#define KCAP 4
#define DIN 16
#define DOUT 16
#define SS 32
#define HW (SS*SS)          // 1024
#define OC (CI*CO*DOUT)     // 1024
#define EPSF 1e-5f

// ---- workspace layout (float element offsets) ----
// votes dead after poolroute; g and cn alias into the votes region.
#define N_VOTES   (BATCH*OC*HW)            // 33,554,432
#define N_PLANE   (BATCH*CO*DOUT*HW)       // 4,194,304
#define OFF_VOTES 0
#define OFF_G     0                        // aliases votes[0 .. N_PLANE)
#define OFF_CN    N_PLANE                  // aliases votes[N_PLANE .. 2N_PLANE)
#define OFF_PMAX  (OFF_VOTES + N_VOTES)
#define OFF_PMEAN (OFF_PMAX + N_PLANE)
#define OFF_ACCM  (OFF_PMEAN + N_PLANE)
#define OFF_WSUM  (OFF_ACCM + N_PLANE)
#define OFF_STATS (OFF_WSUM + N_PLANE)     // total = round-1's proven footprint
#define ST_BNSUM 0
#define ST_BNSQ  8
#define ST_LNSUM 16
#define ST_LNSQ  272
#define STATS_FLOATS 528

__device__ __forceinline__ void wave_reduce_atomic2(float a, float b, float* da, float* db) {
    #pragma unroll
    for (int off = 32; off > 0; off >>= 1) {
        a += __shfl_down(a, off);
        b += __shfl_down(b, off);
    }
    if ((threadIdx.x & 63) == 0) {
        atomicAdd(da, a);
        atomicAdd(db, b);
    }
}

// ---------------- Kernel A: conv2d (caps -> votes) — UNCHANGED (proven) ------
__global__ __launch_bounds__(256) void conv2d_kernel(
        const float* __restrict__ caps, const float* __restrict__ Wt,
        const float* __restrict__ bt, float* __restrict__ votes)
{
    __shared__ float xs[DIN * 18 * 36];
    const int tid = threadIdx.x;
    const int half = blockIdx.x & 1;
    const int oc0 = (blockIdx.x >> 1) * 64;
    const int b = blockIdx.y;
    const int r0 = half * 16;

    for (int i = tid; i < DIN * 18 * 36; i += 256) xs[i] = 0.f;
    __syncthreads();
    const float* capb = caps + (size_t)b * DIN * HW;
    #pragma unroll
    for (int it = 0; it < 9; ++it) {
        const int idx = it * 256 + tid;
        const int din = idx / 144;
        const int rem = idx - din * 144;
        const int row = rem >> 3;
        const int c4 = rem & 7;
        const int gr = r0 - 1 + row;
        if (gr >= 0 && gr < SS) {
            float4 ld = *reinterpret_cast<const float4*>(capb + din * HW + gr * SS + c4 * 4);
            float* dst = &xs[din * (18 * 36) + row * 36 + 1 + c4 * 4];
            dst[0] = ld.x; dst[1] = ld.y; dst[2] = ld.z; dst[3] = ld.w;
        }
    }
    __syncthreads();

    const int ul = tid >> 4;
    const int v0 = (tid & 15) * 2;
    const int U = r0 + ul;

    for (int chunk = 0; chunk < 8; ++chunk) {
        const int occ = oc0 + chunk * 8;
        float acc[8][2];
        #pragma unroll
        for (int j = 0; j < 8; j++) {
            float bj = bt[occ + j];
            acc[j][0] = bj; acc[j][1] = bj;
        }
        for (int din = 0; din < DIN; ++din) {
            float x[3][4];
            #pragma unroll
            for (int r = 0; r < 3; r++)
                #pragma unroll
                for (int c = 0; c < 4; c++)
                    x[r][c] = xs[din * (18 * 36) + (ul + r) * 36 + (v0 + c)];
            #pragma unroll
            for (int j = 0; j < 8; j++) {
                const float* wp = Wt + ((size_t)(occ + j) * DIN + din) * 9;
                #pragma unroll
                for (int ku = 0; ku < 3; ku++)
                    #pragma unroll
                    for (int kv = 0; kv < 3; kv++) {
                        float w = wp[ku * 3 + kv];
                        acc[j][0] += w * x[ku][kv];
                        acc[j][1] += w * x[ku][kv + 1];
                    }
            }
        }
        #pragma unroll
        for (int j = 0; j < 8; j++) {
            float2 st = make_float2(acc[j][0], acc[j][1]);
            *reinterpret_cast<float2*>(votes + ((size_t)b * OC + occ + j) * HW + U * SS + v0) = st;
        }
    }
}

// ------- Kernel B: single-pass einsum -> pool(max,mean) + routing stats ------
// grid 4096: blk = (b*8+o)*16 + d. Thread: 4 px (float4). No LDS, no halo.
// Gate factor (1+s) cancels in softmax, so accm/wsum are gate-independent.
__global__ __launch_bounds__(256) void poolroute_kernel(
        const float* __restrict__ votes, const float* __restrict__ Wv,
        const float* __restrict__ bv,
        float* __restrict__ pmax, float* __restrict__ pmean,
        float* __restrict__ accm_g, float* __restrict__ wsum_g)
{
    const int d = blockIdx.x & 15;
    const int o = (blockIdx.x >> 4) & 7;
    const int b = blockIdx.x >> 7;
    const int px0 = threadIdx.x * 4;

    const float* vpb = votes + ((size_t)b * OC + (size_t)o * DOUT + d) * HW + px0;
    float4 vc[CI];
    #pragma unroll
    for (int c = 0; c < CI; c++)
        vc[c] = *reinterpret_cast<const float4*>(vpb + (size_t)c * (CO * DOUT * HW));

    const float* wv = Wv + (size_t)o * (KCAP * CI) * CI;
    const float* bvo = bv + (size_t)o * (KCAP * CI);

    float4 mx = make_float4(-1e30f, -1e30f, -1e30f, -1e30f);
    float4 sm = make_float4(0.f, 0.f, 0.f, 0.f);
    float4 wsum = make_float4(0.f, 0.f, 0.f, 0.f);
    float4 accm = make_float4(0.f, 0.f, 0.f, 0.f);
    #pragma unroll
    for (int ci = 0; ci < CI; ci++) {
        float4 t0v, t1v, t2v, t3v;
        #define EINSUM_KC(TV, KC) do { \
            const int m_ = (KC) * CI + ci; \
            float bm_ = bvo[m_]; \
            TV = make_float4(bm_, bm_, bm_, bm_); \
            _Pragma("unroll") \
            for (int c = 0; c < CI; c++) { \
                float w_ = wv[m_ * CI + c]; \
                TV.x += w_ * vc[c].x; TV.y += w_ * vc[c].y; \
                TV.z += w_ * vc[c].z; TV.w += w_ * vc[c].w; \
            } } while (0)
        EINSUM_KC(t0v, 0); EINSUM_KC(t1v, 1); EINSUM_KC(t2v, 2); EINSUM_KC(t3v, 3);
        #undef EINSUM_KC
        #define POOL_ROUTE(C) do { \
            mx.C = fmaxf(fmaxf(fmaxf(fmaxf(mx.C, t0v.C), t1v.C), t2v.C), t3v.C); \
            float s1 = t0v.C + t1v.C + t2v.C + t3v.C; \
            sm.C += s1; \
            float s2 = t0v.C * t0v.C + t1v.C * t1v.C + t2v.C * t2v.C + t3v.C * t3v.C; \
            float mean_ = s1 * 0.25f; \
            float v2_ = fmaxf(s2 * 0.25f - mean_ * mean_, 1e-30f); \
            float r_ = rsqrtf(v2_); \
            wsum.C += r_; accm.C += r_ * mean_; \
        } while (0)
        POOL_ROUTE(x); POOL_ROUTE(y); POOL_ROUTE(z); POOL_ROUTE(w);
        #undef POOL_ROUTE
    }
    const size_t gbase = (((size_t)b * CO + o) * DOUT + d) * HW + px0;
    const float inv = 1.f / 32.f;
    *reinterpret_cast<float4*>(&pmax[gbase]) = mx;
    *reinterpret_cast<float4*>(&pmean[gbase]) =
        make_float4(sm.x * inv, sm.y * inv, sm.z * inv, sm.w * inv);
    *reinterpret_cast<float4*>(&accm_g[gbase]) = accm;
    *reinterpret_cast<float4*>(&wsum_g[gbase]) = wsum;
}

// ------- Kernel C: 3x3x3 stencil over pooled planes + BN partials ------------
// grid 1024: blk = b*32 + o*4 + uslab. Block owns 8 u-rows x all 16 d.
// LDS: 2 x 16d x 10u x 32v x 4B = 40,960 B.
__global__ __launch_bounds__(256) void stencil_kernel(
        const float* __restrict__ pmax, const float* __restrict__ pmean,
        const float* __restrict__ Wsp, float* __restrict__ g, float* __restrict__ stats)
{
    __shared__ float smx[DOUT][10][SS];
    __shared__ float smn[DOUT][10][SS];
    const int tid = threadIdx.x;
    const int uslab = blockIdx.x & 3;
    const int o = (blockIdx.x >> 2) & 7;
    const int b = blockIdx.x >> 5;
    const size_t base = ((size_t)(b * CO + o) * DOUT) * HW;

    // load 16d x 10u x 32v (u halo zero-filled): 1280 float4s
    #pragma unroll
    for (int it = 0; it < 5; ++it) {
        const int idx = it * 256 + tid;          // 0..1279
        const int d = idx / 80;
        const int rem = idx - d * 80;
        const int row = rem >> 3;                // 0..9
        const int c4 = rem & 7;
        const int gu = uslab * 8 - 1 + row;
        float4 vx = make_float4(0.f, 0.f, 0.f, 0.f);
        float4 vn = make_float4(0.f, 0.f, 0.f, 0.f);
        if (gu >= 0 && gu < SS) {
            const size_t off = base + (size_t)d * HW + gu * SS + c4 * 4;
            vx = *reinterpret_cast<const float4*>(pmax + off);
            vn = *reinterpret_cast<const float4*>(pmean + off);
        }
        *reinterpret_cast<float4*>(&smx[d][row][c4 * 4]) = vx;
        *reinterpret_cast<float4*>(&smn[d][row][c4 * 4]) = vn;
    }
    __syncthreads();

    float bnsum = 0.f, bnsq = 0.f;
    #pragma unroll
    for (int it = 0; it < 16; ++it) {
        const int idx = it * 256 + tid;          // 0..4095
        const int d = idx >> 8;
        const int ul = (idx >> 5) & 7;
        const int v = idx & 31;
        float acc = 0.f;
        #pragma unroll
        for (int dd = -1; dd <= 1; dd++) {
            const int dp = d + dd;
            if (dp < 0 || dp >= DOUT) continue;
            #pragma unroll
            for (int du = 0; du < 3; du++) {
                const int row = ul + du;         // LDS rows 0..9 (u halo inside)
                #pragma unroll
                for (int dv = -1; dv <= 1; dv++) {
                    const int vv = v + dv;
                    if (vv < 0 || vv >= SS) continue;
                    const int widx = (dd + 1) * 9 + du * 3 + (dv + 1);
                    acc += Wsp[widx] * smx[dp][row][vv] + Wsp[27 + widx] * smn[dp][row][vv];
                }
            }
        }
        const int gu = uslab * 8 + ul;
        g[base + (size_t)d * HW + gu * SS + v] = acc;
        bnsum += acc; bnsq += acc * acc;
    }
    wave_reduce_atomic2(bnsum, bnsq, &stats[ST_BNSUM + o], &stats[ST_BNSQ + o]);
}

// ------- Kernel D: BN -> sigmoid gate -> caps_next + LN partials -------------
// grid 4096: blk = (b*8+o)*16 + d. Thread: 4 px.
__global__ __launch_bounds__(256) void finalize_kernel(
        const float* __restrict__ g, const float* __restrict__ accm_g,
        const float* __restrict__ wsum_g,
        const float* __restrict__ bn_gamma, const float* __restrict__ bn_beta,
        float* __restrict__ cn, float* __restrict__ stats)
{
    const int d = blockIdx.x & 15;
    const int o = (blockIdx.x >> 4) & 7;
    const int b = blockIdx.x >> 7;
    const int px0 = threadIdx.x * 4;

    const float nbn = 1.f / (float)(BATCH * DOUT * HW);
    const float mu = stats[ST_BNSUM + o] * nbn;
    const float var = fmaxf(stats[ST_BNSQ + o] * nbn - mu * mu, 0.f);
    const float rstd = rsqrtf(var + EPSF);
    const float gam = bn_gamma[0], bet = bn_beta[0];

    const size_t gbase = (((size_t)b * CO + o) * DOUT + d) * HW + px0;
    float4 g4 = *reinterpret_cast<const float4*>(&g[gbase]);
    float4 a4 = *reinterpret_cast<const float4*>(&accm_g[gbase]);
    float4 w4 = *reinterpret_cast<const float4*>(&wsum_g[gbase]);
    float4 cnv;
    cnv.x = (1.f + 1.f / (1.f + expf(-((g4.x - mu) * rstd * gam + bet)))) * a4.x / w4.x;
    cnv.y = (1.f + 1.f / (1.f + expf(-((g4.y - mu) * rstd * gam + bet)))) * a4.y / w4.y;
    cnv.z = (1.f + 1.f / (1.f + expf(-((g4.z - mu) * rstd * gam + bet)))) * a4.z / w4.z;
    cnv.w = (1.f + 1.f / (1.f + expf(-((g4.w - mu) * rstd * gam + bet)))) * a4.w / w4.w;
    *reinterpret_cast<float4*>(&cn[gbase]) = cnv;

    float s = cnv.x + cnv.y + cnv.z + cnv.w;
    float sq = cnv.x * cnv.x + cnv.y * cnv.y + cnv.z * cnv.z + cnv.w * cnv.w;
    wave_reduce_atomic2(s, sq, &stats[ST_LNSUM + b * CO + o], &stats[ST_LNSQ + b * CO + o]);
}

// ---------------- Kernel E: LayerNorm + transpose-out ------------------------
__global__ __launch_bounds__(256) void ln_kernel(
        const float* __restrict__ cn, const float* __restrict__ stats,
        const float* __restrict__ lng, const float* __restrict__ lnb,
        float* __restrict__ out)
{
    const int bo = blockIdx.x;
    const int b = bo >> 3, o = bo & 7;
    const float nln = 1.f / 16384.f;
    const float mu = stats[ST_LNSUM + bo] * nln;
    const float var = fmaxf(stats[ST_LNSQ + bo] * nln - mu * mu, 0.f);
    const float rstd = rsqrtf(var + EPSF);
    const float* src = cn + (size_t)bo * 16384;
    float* dst = out + ((size_t)o * BATCH + b) * 16384;
    #pragma unroll
    for (int i = 0; i < 16; i++) {
        const int e = i * 1024 + threadIdx.x * 4;
        float4 x = *reinterpret_cast<const float4*>(src + e);
        float4 gm = *reinterpret_cast<const float4*>(lng + e);
        float4 bb = *reinterpret_cast<const float4*>(lnb + e);
        float4 y;
        y.x = (x.x - mu) * rstd * gm.x + bb.x;
        y.y = (x.y - mu) * rstd * gm.y + bb.y;
        y.z = (x.z - mu) * rstd * gm.z + bb.z;
        y.w = (x.w - mu) * rstd * gm.w + bb.w;
        *reinterpret_cast<float4*>(dst + e) = y;
    }
}

extern "C" void kernel_launch(void* const* d_in, const int* in_sizes, int n_in,
                              void* d_out, int out_size, void* d_ws, size_t ws_size,
                              hipStream_t stream) {
    const float* caps = (const float*)d_in[0];
    const float* Wt   = (const float*)d_in[1];
    const float* bt   = (const float*)d_in[2];
    const float* Wv   = (const float*)d_in[3];
    const float* bv   = (const float*)d_in[4];
    const float* Wsp  = (const float*)d_in[5];
    const float* bng  = (const float*)d_in[6];
    const float* bnb  = (const float*)d_in[7];
    const float* lng  = (const float*)d_in[8];
    const float* lnb  = (const float*)d_in[9];
    float* ws = (float*)d_ws;
    float* votes = ws + OFF_VOTES;
    float* g     = ws + OFF_G;      // aliases votes (dead after poolroute)
    float* cn    = ws + OFF_CN;     // aliases votes
    float* pmax  = ws + OFF_PMAX;
    float* pmean = ws + OFF_PMEAN;
    float* accm  = ws + OFF_ACCM;
    float* wsum  = ws + OFF_WSUM;
    float* stats = ws + OFF_STATS;
    float* out = (float*)d_out;

    hipMemsetAsync(stats, 0, STATS_FLOATS * sizeof(float), stream);
    conv2d_kernel<<<dim3(32, 32), 256, 0, stream>>>(caps, Wt, bt, votes);
    poolroute_kernel<<<4096, 256, 0, stream>>>(votes, Wv, bv, pmax, pmean, accm, wsum);
    stencil_kernel<<<1024, 256, 0, stream>>>(pmax, pmean, Wsp, g, stats);
    finalize_kernel<<<4096, 256, 0, stream>>>(g, accm, wsum, bng, bnb, cn, stats);
    ln_kernel<<<256, 256, 0, stream>>>(cn, stats, lng, lnb, out);
}